// Round 3
// baseline (2001.097 us; speedup 1.0000x reference)
//
#include <hip/hip_runtime.h>
#include <hip/hip_bf16.h>

#define CI 192
#define LL_ 4096

__device__ __forceinline__ float wred64(float v){
  #pragma unroll
  for (int off = 32; off; off >>= 1) v += __shfl_down(v, off);
  return v;
}

__global__ __launch_bounds__(256) void k_zero(float* __restrict__ p, int n){
  int i = blockIdx.x*256 + threadIdx.x;
  if (i < n) p[i] = 0.f;
}

// ------------------------------------------------ K1: RMSNorm + in_proj
__global__ __launch_bounds__(128) void k_rms_inproj(const float* __restrict__ x,
    const float* __restrict__ rmsw, const float* __restrict__ ipw,
    float* __restrict__ xc, float* __restrict__ zb){
  int bl = blockIdx.x;
  int b = bl >> 12, l = bl & 4095;
  int t = threadIdx.x;
  __shared__ float xrow[96];
  __shared__ float red[2];
  float v = (t < 96) ? x[(size_t)bl*96 + t] : 0.f;
  float s = wred64(v*v);
  if ((t & 63) == 0) red[t >> 6] = s;
  __syncthreads();
  float rms = rsqrtf((red[0] + red[1]) * (1.0f/96.0f) + 1e-5f);
  if (t < 96) xrow[t] = v * rms * rmsw[t];
  __syncthreads();
  for (int o = t; o < 384; o += 128){
    const float* wr = ipw + (size_t)o*96;
    float acc = 0.f;
    #pragma unroll 4
    for (int d = 0; d < 96; d++) acc += xrow[d]*wr[d];
    if (o < 192) xc[((size_t)b*CI + o)*LL_ + l] = acc;
    else         zb[(size_t)bl*CI + (o-192)] = acc;
  }
}

// ------------------------------------------------ K2: forward rfft2 (ortho)
__global__ __launch_bounds__(256) void k_dft_fwd(const float* __restrict__ xc,
    float* __restrict__ fre, float* __restrict__ fim, float* __restrict__ fab){
  int plane = blockIdx.x;
  const float* X = xc + (size_t)plane*4096;
  __shared__ float sx[4096];
  __shared__ float t1r[2112], t1i[2112];
  __shared__ float ct[64], st[64];
  int tid = threadIdx.x;
  for (int i = tid; i < 4096; i += 256) sx[i] = X[i];
  if (tid < 64){ ct[tid] = cospif((float)tid/32.0f); st[tid] = sinpif((float)tid/32.0f); }
  __syncthreads();
  for (int idx = tid; idx < 2112; idx += 256){
    int h = idx/33, k = idx - h*33;
    float sr = 0.f, si = 0.f;
    for (int w = 0; w < 64; w++){
      int t = (w*k) & 63; float v = sx[h*64 + w];
      sr += v*ct[t]; si -= v*st[t];
    }
    t1r[idx] = sr; t1i[idx] = si;
  }
  __syncthreads();
  for (int idx = tid; idx < 2112; idx += 256){
    int f = idx/33, k = idx - f*33;
    float sr = 0.f, si = 0.f;
    for (int h = 0; h < 64; h++){
      int t = (h*f) & 63; float c = ct[t], s = st[t];
      float ar = t1r[h*33 + k], ai = t1i[h*33 + k];
      sr += ar*c + ai*s;
      si += ai*c - ar*s;
    }
    sr *= (1.0f/64.0f); si *= (1.0f/64.0f);
    size_t o = (size_t)plane*2112 + idx;
    fre[o] = sr; fim[o] = si; fab[o] = sqrtf(sr*sr + si*si);
  }
}

// ------------------------------------------------ K3: m = gelu(W1 @ |xf| + b1)
__global__ __launch_bounds__(256) void k_cmix1(const float* __restrict__ fab,
    const float* __restrict__ w1, const float* __restrict__ b1, float* __restrict__ m){
  int id = blockIdx.x*256 + threadIdx.x;
  int p = id % 2112; int rest = id / 2112; int o = rest % 192; int b = rest / 192;
  const float* ib = fab + (size_t)b*CI*2112 + p;
  const float* wr = w1 + (size_t)o*CI;
  float acc = b1[o];
  #pragma unroll 4
  for (int c = 0; c < 192; c++) acc += ib[(size_t)c*2112] * wr[c];
  m[id] = 0.5f*acc*(1.0f + erff(acc*0.70710678118654752f));
}

// ------------------------------------------------ K4: mag = W2 @ m + b2; in-place mag*e^{i angle}
__global__ __launch_bounds__(256) void k_cmix2(const float* __restrict__ m,
    const float* __restrict__ w2, const float* __restrict__ bi2,
    float* __restrict__ fre, float* __restrict__ fim, const float* __restrict__ fab){
  int id = blockIdx.x*256 + threadIdx.x;
  int p = id % 2112; int rest = id / 2112; int o = rest % 192; int b = rest / 192;
  const float* ib = m + (size_t)b*CI*2112 + p;
  const float* wr = w2 + (size_t)o*CI;
  float acc = bi2[o];
  #pragma unroll 4
  for (int c = 0; c < 192; c++) acc += ib[(size_t)c*2112] * wr[c];
  float ab = fab[id];
  float re, im;
  if (ab > 1e-30f){ float sc = acc/ab; re = sc*fre[id]; im = sc*fim[id]; }
  else { re = acc; im = 0.f; }
  fre[id] = re; fim[id] = im;
}

// ------------------------------------------------ K5: Haar DWT
__global__ __launch_bounds__(256) void k_dwt(const float* __restrict__ xc,
    float* __restrict__ ll, float* __restrict__ lh, float* __restrict__ hl, float* __restrict__ hh){
  int id = blockIdx.x*256 + threadIdx.x;
  int x2 = id & 31; int y2 = (id >> 5) & 31; size_t plane = (size_t)(id >> 10);
  const float* p = xc + plane*4096;
  int h = y2 << 1, w = x2 << 1;
  float a_ = p[h*64 + w],     b_ = p[h*64 + w + 1];
  float c_ = p[(h+1)*64 + w], d_ = p[(h+1)*64 + w + 1];
  ll[id] = (a_+b_+c_+d_)*0.5f; lh[id] = (a_-b_+c_-d_)*0.5f;
  hl[id] = (a_+b_-c_-d_)*0.5f; hh[id] = (a_-b_-c_+d_)*0.5f;
}

// ------------------------------------------------ K6: full 3x3 conv on (lh,hl,hh), c-split partials
__global__ __launch_bounds__(256) void k_wconv(const float* __restrict__ in,
    const float* __restrict__ ww, float* __restrict__ outA, float* __restrict__ outB){
  int bid = blockIdx.x;                // ((ch*3+t)*4+b)*24+oc
  int oc = bid % 24; int b = (bid/24) & 3; int t = (bid/96) % 3; int ch = bid / 288;
  int o0 = oc*8;
  const float* inb = in + (size_t)t*786432 + (size_t)b*196608;
  float* outb = (ch ? outB : outA) + (size_t)t*786432 + (size_t)b*196608;
  __shared__ float pl[1024];
  __shared__ float wl[72];
  int tid = threadIdx.x;
  float acc[4][8];
  #pragma unroll
  for (int j = 0; j < 4; j++)
    #pragma unroll
    for (int o = 0; o < 8; o++) acc[j][o] = 0.f;
  int c0 = ch*96;
  for (int cc = 0; cc < 96; cc++){
    int c = c0 + cc;
    __syncthreads();
    #pragma unroll
    for (int j = 0; j < 4; j++) pl[tid + j*256] = inb[(size_t)c*1024 + tid + j*256];
    if (tid < 72){ int o = tid/9, q = tid - o*9; wl[tid] = ww[((size_t)(o0+o)*192 + c)*9 + q]; }
    __syncthreads();
    #pragma unroll
    for (int j = 0; j < 4; j++){
      int p = tid + j*256; int y = p >> 5, x = p & 31;
      float nb[9];
      #pragma unroll
      for (int ky = 0; ky < 3; ky++)
        #pragma unroll
        for (int kx = 0; kx < 3; kx++){
          int yy = y + ky - 1, xx = x + kx - 1;
          nb[ky*3+kx] = (yy >= 0 && yy < 32 && xx >= 0 && xx < 32) ? pl[yy*32 + xx] : 0.f;
        }
      #pragma unroll
      for (int o = 0; o < 8; o++){
        float s = 0.f;
        #pragma unroll
        for (int q = 0; q < 9; q++) s += nb[q]*wl[o*9 + q];
        acc[j][o] += s;
      }
    }
  }
  #pragma unroll
  for (int o = 0; o < 8; o++)
    #pragma unroll
    for (int j = 0; j < 4; j++)
      outb[(size_t)(o0+o)*1024 + tid + j*256] = acc[j][o];
}

// ------------------------------------------------ K7: xc = 2*xc + idwt(ll, conv+bias)  (in place)
__global__ __launch_bounds__(256) void k_fcomb(float* __restrict__ xc,
    const float* __restrict__ ll, const float* __restrict__ w2a, const float* __restrict__ w2b,
    const float* __restrict__ wb){
  int id = blockIdx.x*256 + threadIdx.x;
  int p = id & 4095; size_t plane = (size_t)(id >> 12);
  int c = (int)(plane % 192);
  int h = p >> 6, w = p & 63;
  size_t q = plane*1024 + (size_t)(h >> 1)*32 + (w >> 1);
  float bia = wb[c];
  float LLv = ll[q];
  float LH = w2a[q]           + w2b[q]           + bia;
  float HL = w2a[786432 + q]  + w2b[786432 + q]  + bia;
  float HH = w2a[1572864 + q] + w2b[1572864 + q] + bia;
  float v;
  bool hb = (h & 1), wbit = (w & 1);
  if (!hb && !wbit)      v = (LLv + LH + HL + HH)*0.5f;
  else if (!hb && wbit)  v = (LLv - LH + HL - HH)*0.5f;
  else if (hb && !wbit)  v = (LLv + LH - HL - HH)*0.5f;
  else                   v = (LLv - LH - HL + HH)*0.5f;
  xc[id] = 2.0f*xc[id] + v;
}

// ------------------------------------------------ K8: irfft2 (ortho), accumulate into xc
__global__ __launch_bounds__(256) void k_dft_inv(const float* __restrict__ fre2,
    const float* __restrict__ fim2, float* __restrict__ xc){
  int plane = blockIdx.x;
  __shared__ float gr[2112], gi[2112], ur[2112], ui[2112];
  __shared__ float ct[64], st[64];
  int tid = threadIdx.x;
  for (int i = tid; i < 2112; i += 256){
    size_t o = (size_t)plane*2112 + i;
    gr[i] = fre2[o]; gi[i] = fim2[o];
  }
  if (tid < 64){ ct[tid] = cospif((float)tid/32.0f); st[tid] = sinpif((float)tid/32.0f); }
  __syncthreads();
  for (int idx = tid; idx < 2112; idx += 256){
    int h = idx/33, k = idx - h*33;
    float sr = 0.f, si = 0.f;
    for (int f = 0; f < 64; f++){
      int t = (f*h) & 63; float c = ct[t], s = st[t];
      float ar = gr[f*33 + k], ai = gi[f*33 + k];
      sr += ar*c - ai*s;
      si += ai*c + ar*s;
    }
    ur[idx] = sr; ui[idx] = si;
  }
  __syncthreads();
  for (int p = tid; p < 4096; p += 256){
    int h = p >> 6, w = p & 63;
    float acc = 0.f;
    for (int k = 0; k <= 32; k++){
      int t = (k*w) & 63;
      float re = ur[h*33 + k]*ct[t] - ui[h*33 + k]*st[t];
      acc += (k == 0 || k == 32) ? re : 2.0f*re;
    }
    xc[(size_t)plane*4096 + p] += acc*(1.0f/64.0f);
  }
}

// ------------------------------------------------ K9: depthwise 3x3 + SiLU -> ab
__global__ __launch_bounds__(256) void k_dwconv(const float* __restrict__ xc2,
    const float* __restrict__ dww, const float* __restrict__ dwb, float* __restrict__ ab){
  int id = blockIdx.x*256 + threadIdx.x;
  int p = id & 4095; size_t plane = (size_t)(id >> 12); int c = (int)(plane % 192);
  int h = p >> 6, w = p & 63;
  const float* pp = xc2 + plane*4096;
  float acc = dwb[c];
  #pragma unroll
  for (int ky = 0; ky < 3; ky++){
    int yy = h + ky - 1; if (yy < 0 || yy > 63) continue;
    #pragma unroll
    for (int kx = 0; kx < 3; kx++){
      int xx = w + kx - 1; if (xx < 0 || xx > 63) continue;
      acc += pp[yy*64 + xx]*dww[c*9 + ky*3 + kx];
    }
  }
  ab[id] = acc / (1.f + expf(-acc));
}

// ------------------------------------------------ K10: x_proj; emit Bs, Cs, dts(rank6)
__global__ __launch_bounds__(256) void k_xproj(const float* __restrict__ ab,
    const float* __restrict__ xpw,
    float* __restrict__ Bsb, float* __restrict__ Csb, float* __restrict__ dlsb){
  int bid = blockIdx.x;                 // (b*4+k)*64 + s
  int s = bid & 63; int k = (bid >> 6) & 3; int b = bid >> 8;
  int tid = threadIdx.x;
  __shared__ float als[192][65];
  __shared__ float dls[6][64];
  int l0 = s << 6;
  for (int idx = tid; idx < 192*64; idx += 256){
    int d = idx >> 6, i = idx & 63;
    int pl;
    if (k == 0)      pl = l0 + i;
    else if (k == 1) pl = (i << 6) + s;
    else if (k == 2) pl = 4095 - (l0 + i);
    else             pl = 4095 - ((i << 6) + s);
    als[d][i] = ab[((size_t)b*192 + d)*4096 + pl];
  }
  __syncthreads();
  for (int j = tid; j < 38*64; j += 256){
    int cp = j >> 6, i = j & 63;
    const float* wr = xpw + ((size_t)k*38 + cp)*192;
    float acc = 0.f;
    #pragma unroll 4
    for (int d = 0; d < 192; d++) acc += als[d][i]*wr[d];
    if (cp < 6) dls[cp][i] = acc;
    else if (cp < 22) Bsb[((size_t)(b*4 + k)*16 + (cp - 6 ))*4096 + l0 + i] = acc;
    else              Csb[((size_t)(b*4 + k)*16 + (cp - 22))*4096 + l0 + i] = acc;
  }
  __syncthreads();
  size_t dbase = (size_t)((b*4 + k)*64 + s)*384;
  for (int j = tid; j < 384; j += 256){
    int i = j/6, r = j - i*6;
    dlsb[dbase + j] = dls[r][i];
  }
}

// ------------------------------------------------ K11: scan phase A — per-segment (P,Q)
__global__ __launch_bounds__(192) void k_scanA(const float* __restrict__ ab,
    const float* __restrict__ dlsb, const float* __restrict__ Bsb,
    const float* __restrict__ dtw, const float* __restrict__ dtb,
    const float* __restrict__ alog, float* __restrict__ Pb, float* __restrict__ Qb){
  int bid = blockIdx.x; int s = bid & 63; int k = (bid >> 6) & 3; int b = bid >> 8;
  int c = threadIdx.x; int bk = b*4 + k;
  __shared__ float sdl[384];
  __shared__ float sB[16][64];
  size_t dbase = (size_t)(bk*64 + s)*384;
  for (int j = c; j < 384; j += 192) sdl[j] = dlsb[dbase + j];
  for (int j = c; j < 1024; j += 192){ int n = j >> 6, i = j & 63;
    sB[n][i] = Bsb[((size_t)bk*16 + n)*4096 + (s << 6) + i]; }
  __syncthreads();
  float A[16], P[16], Q[16];
  const float* arow = alog + ((size_t)k*192 + c)*16;
  #pragma unroll
  for (int n = 0; n < 16; n++){ A[n] = -expf(arow[n]); P[n] = 1.f; Q[n] = 0.f; }
  float dw[6];
  #pragma unroll
  for (int r = 0; r < 6; r++) dw[r] = dtw[((size_t)k*192 + c)*6 + r];
  float db = dtb[k*192 + c];
  const float* abp = ab + ((size_t)b*192 + c)*4096;
  int p0, pst;
  if (k == 0){ p0 = s << 6;        pst = 1;  }
  else if (k == 1){ p0 = s;        pst = 64; }
  else if (k == 2){ p0 = 4095 - (s << 6); pst = -1; }
  else { p0 = 4095 - s;            pst = -64; }
  for (int i = 0; i < 64; i++){
    float u = abp[p0 + pst*i];
    float acc = db;
    #pragma unroll
    for (int r = 0; r < 6; r++) acc += sdl[i*6 + r]*dw[r];
    float dl = fmaxf(acc, 0.f) + log1pf(expf(-fabsf(acc)));
    float du = dl*u;
    #pragma unroll
    for (int n = 0; n < 16; n++){
      float e = expf(dl*A[n]);
      P[n] *= e;
      Q[n] = Q[n]*e + du*sB[n][i];
    }
  }
  size_t pbase = ((size_t)(bk*64 + s)*16)*192 + c;
  #pragma unroll
  for (int n = 0; n < 16; n++){ Pb[pbase + (size_t)n*192] = P[n]; Qb[pbase + (size_t)n*192] = Q[n]; }
}

// ------------------------------------------------ K12: scan phase B — prefix over 64 segments
__global__ __launch_bounds__(256) void k_scanB(const float* __restrict__ Pb,
    const float* __restrict__ Qb, float* __restrict__ hinb){
  int id = blockIdx.x*256 + threadIdx.x;   // (bk*16+n)*192+c -> 49152
  int c = id % 192; int rest = id / 192; int n = rest % 16; int bk = rest / 16;
  float h = 0.f;
  for (int s = 0; s < 64; s++){
    size_t o = (((size_t)bk*64 + s)*16 + n)*192 + c;
    hinb[o] = h;
    h = Pb[o]*h + Qb[o];
  }
}

// ------------------------------------------------ K13: scan phase C — replay, scatter-add into yb
__global__ __launch_bounds__(192) void k_scanC(const float* __restrict__ ab,
    const float* __restrict__ dlsb, const float* __restrict__ Bsb, const float* __restrict__ Csb,
    const float* __restrict__ hinb, const float* __restrict__ dtw, const float* __restrict__ dtb,
    const float* __restrict__ alog, const float* __restrict__ Dsp, float* __restrict__ yb){
  int bid = blockIdx.x; int s = bid & 63; int k = (bid >> 6) & 3; int b = bid >> 8;
  int c = threadIdx.x; int bk = b*4 + k;
  __shared__ float sdl[384];
  __shared__ float sB[16][64];
  __shared__ float sC[16][64];
  size_t dbase = (size_t)(bk*64 + s)*384;
  for (int j = c; j < 384; j += 192) sdl[j] = dlsb[dbase + j];
  for (int j = c; j < 1024; j += 192){ int n = j >> 6, i = j & 63;
    size_t o = ((size_t)bk*16 + n)*4096 + (s << 6) + i;
    sB[n][i] = Bsb[o]; sC[n][i] = Csb[o]; }
  __syncthreads();
  float A[16], h[16];
  const float* arow = alog + ((size_t)k*192 + c)*16;
  #pragma unroll
  for (int n = 0; n < 16; n++) A[n] = -expf(arow[n]);
  size_t hbase = ((size_t)(bk*64 + s)*16)*192 + c;
  #pragma unroll
  for (int n = 0; n < 16; n++) h[n] = hinb[hbase + (size_t)n*192];
  float dw[6];
  #pragma unroll
  for (int r = 0; r < 6; r++) dw[r] = dtw[((size_t)k*192 + c)*6 + r];
  float db = dtb[k*192 + c];
  float Dc = Dsp[k*192 + c];
  const float* abp = ab + ((size_t)b*192 + c)*4096;
  int p0, pst;
  if (k == 0){ p0 = s << 6;        pst = 1;  }
  else if (k == 1){ p0 = s;        pst = 64; }
  else if (k == 2){ p0 = 4095 - (s << 6); pst = -1; }
  else { p0 = 4095 - s;            pst = -64; }
  for (int i = 0; i < 64; i++){
    int pl = p0 + pst*i;
    float u = abp[pl];
    float acc = db;
    #pragma unroll
    for (int r = 0; r < 6; r++) acc += sdl[i*6 + r]*dw[r];
    float dl = fmaxf(acc, 0.f) + log1pf(expf(-fabsf(acc)));
    float du = dl*u;
    float y = 0.f;
    #pragma unroll
    for (int n = 0; n < 16; n++){
      float e = expf(dl*A[n]);
      h[n] = h[n]*e + du*sB[n][i];
      y += h[n]*sC[n][i];
    }
    y += u*Dc;
    atomicAdd(&yb[((size_t)b*4096 + pl)*192 + c], y);  // combine perm == gather perm (involution)
  }
}

// ------------------------------------------------ K14: symmetry enhance
__global__ __launch_bounds__(256) void k_enh(const float* __restrict__ yb,
    const float* __restrict__ symw, float* __restrict__ yfb){
  int id = blockIdx.x*256 + threadIdx.x;
  int c = id % 192; int rest = id / 192; int l = rest & 4095; int b = rest >> 12;
  int w = l & 63; int lr = (l | 63) - w;
  float v  = yb[id];
  float vr = yb[(((size_t)b << 12) + lr)*192 + c];
  float wg = 1.f/(1.f + expf(-symw[0]));
  float enh = v*(1.f - wg) + 0.5f*(v + vr)*wg;
  yfb[id] = v + 0.2f*enh;
}

// ------------------------------------------------ K15: LayerNorm + SiLU(z) + out_proj + residual (f32 out)
__global__ __launch_bounds__(192) void k_final(const float* __restrict__ yf,
    const float* __restrict__ zb, const float* __restrict__ g, const float* __restrict__ bta,
    const float* __restrict__ opw, const float* __restrict__ x, float* __restrict__ out){
  int bl = blockIdx.x; int c = threadIdx.x;
  __shared__ float sv[192];
  __shared__ float r1[3], r2[3];
  float v = yf[(size_t)bl*192 + c];
  float s1 = wred64(v); float s2 = wred64(v*v);
  if ((c & 63) == 0){ r1[c >> 6] = s1; r2[c >> 6] = s2; }
  __syncthreads();
  float mu  = (r1[0] + r1[1] + r1[2]) * (1.0f/192.0f);
  float var = (r2[0] + r2[1] + r2[2]) * (1.0f/192.0f) - mu*mu;
  float rs = rsqrtf(var + 1e-5f);
  float yn = (v - mu)*rs*g[c] + bta[c];
  float zv = zb[(size_t)bl*192 + c];
  sv[c] = yn * (zv / (1.f + expf(-zv)));
  __syncthreads();
  if (c < 96){
    const float* wr = opw + (size_t)c*192;
    float acc = 0.f;
    #pragma unroll 4
    for (int j = 0; j < 192; j++) acc += sv[j]*wr[j];
    out[(size_t)bl*96 + c] = acc + x[(size_t)bl*96 + c];
  }
}

// ================================================================ host
extern "C" void kernel_launch(void* const* d_in, const int* in_sizes, int n_in,
                              void* d_out, int out_size, void* d_ws, size_t ws_size,
                              hipStream_t stream){
  (void)in_sizes; (void)n_in; (void)out_size; (void)ws_size;
  const float* ix   = (const float*)d_in[0];
  const float* ipw  = (const float*)d_in[1];
  const float* fw1  = (const float*)d_in[2];
  const float* fb1  = (const float*)d_in[3];
  const float* fw2  = (const float*)d_in[4];
  const float* fb2  = (const float*)d_in[5];
  const float* ww   = (const float*)d_in[6];
  const float* wb   = (const float*)d_in[7];
  const float* dww  = (const float*)d_in[8];
  const float* dwb  = (const float*)d_in[9];
  const float* symw = (const float*)d_in[10];
  const float* xpw  = (const float*)d_in[11];
  const float* dtw  = (const float*)d_in[12];
  const float* dtb  = (const float*)d_in[13];
  const float* alog = (const float*)d_in[14];
  const float* Dsp  = (const float*)d_in[15];
  const float* ong  = (const float*)d_in[16];
  const float* onb  = (const float*)d_in[17];
  const float* opw  = (const float*)d_in[18];
  const float* rmsw = (const float*)d_in[19];

  float* W = (float*)d_ws;
  const size_t SZ_BLC = 3145728, SZ_F = 1622016, SZ_H = 786432;
  float* zb  = W;
  float* ab  = zb + SZ_BLC;
  float* R0  = ab + SZ_BLC;
  // phase 1 (freq/wavelet) in R0
  float* xc  = R0;                  // also xc2 in-place
  float* fre = xc  + SZ_BLC;        // also fre2 in-place
  float* fim = fre + SZ_F;
  float* fab = fim + SZ_F;
  float* mb  = fab + SZ_F;
  float* llb = mb  + SZ_F;
  float* lhb = llb + SZ_H;          // lh,hl,hh consecutive
  float* w2a = lhb + 3*SZ_H;
  float* w2b = w2a + 3*SZ_H;
  // phase 2 (scan) reuses R0 after k_dwconv
  float* Bsb  = R0;
  float* Csb  = Bsb + 1048576;
  float* dlsb = Csb + 1048576;
  float* Pb   = dlsb + 393216;
  float* Qb   = Pb + SZ_BLC;
  float* hinb = Qb + SZ_BLC;
  float* yb   = hinb + SZ_BLC;
  float* yfb  = yb + SZ_BLC;

  hipLaunchKernelGGL(k_rms_inproj, dim3(4*4096), dim3(128), 0, stream, ix, rmsw, ipw, xc, zb);
  hipLaunchKernelGGL(k_dft_fwd,    dim3(4*192),  dim3(256), 0, stream, xc, fre, fim, fab);
  hipLaunchKernelGGL(k_cmix1,      dim3(6336),   dim3(256), 0, stream, fab, fw1, fb1, mb);
  hipLaunchKernelGGL(k_cmix2,      dim3(6336),   dim3(256), 0, stream, mb, fw2, fb2, fre, fim, fab);
  hipLaunchKernelGGL(k_dwt,        dim3(3072),   dim3(256), 0, stream, xc, llb, lhb, lhb + SZ_H, lhb + 2*SZ_H);
  hipLaunchKernelGGL(k_wconv,      dim3(576),    dim3(256), 0, stream, lhb, ww, w2a, w2b);
  hipLaunchKernelGGL(k_fcomb,      dim3(12288),  dim3(256), 0, stream, xc, llb, w2a, w2b, wb);
  hipLaunchKernelGGL(k_dft_inv,    dim3(4*192),  dim3(256), 0, stream, fre, fim, xc);
  hipLaunchKernelGGL(k_dwconv,     dim3(12288),  dim3(256), 0, stream, xc, dww, dwb, ab);
  hipLaunchKernelGGL(k_xproj,      dim3(1024),   dim3(256), 0, stream, ab, xpw, Bsb, Csb, dlsb);
  hipLaunchKernelGGL(k_scanA,      dim3(1024),   dim3(192), 0, stream, ab, dlsb, Bsb, dtw, dtb, alog, Pb, Qb);
  hipLaunchKernelGGL(k_scanB,      dim3(192),    dim3(256), 0, stream, Pb, Qb, hinb);
  hipLaunchKernelGGL(k_zero,       dim3(12288),  dim3(256), 0, stream, yb, (int)SZ_BLC);
  hipLaunchKernelGGL(k_scanC,      dim3(1024),   dim3(192), 0, stream, ab, dlsb, Bsb, Csb, hinb, dtw, dtb, alog, Dsp, yb);
  hipLaunchKernelGGL(k_enh,        dim3(12288),  dim3(256), 0, stream, yb, symw, yfb);
  hipLaunchKernelGGL(k_final,      dim3(4*4096), dim3(192), 0, stream, yfb, zb, ong, onb, opw, ix, (float*)d_out);
}

// Round 4
// 1084.193 us; speedup vs baseline: 1.8457x; 1.8457x over previous
//
#include <hip/hip_runtime.h>
#include <hip/hip_bf16.h>

#define CI 192
#define LL_ 4096

__global__ __launch_bounds__(256) void k_zero(float* __restrict__ p, int n){
  int i = blockIdx.x*256 + threadIdx.x;
  if (i < n) p[i] = 0.f;
}

// ------------------------------------------------ K1: RMSNorm + in_proj (tiled GEMM)
// grid: b(4) x lt(64) x og(4); block computes 96 outputs x 64 l-positions
// xc layout [b][192][4096]; zT layout [b][192][4096]
__global__ __launch_bounds__(256) void k_rms_inproj(const float* __restrict__ x,
    const float* __restrict__ rmsw, const float* __restrict__ ipw,
    float* __restrict__ xc, float* __restrict__ zT){
  int og = blockIdx.x & 3; int lt = (blockIdx.x >> 2) & 63; int b = blockIdx.x >> 8;
  int l0 = lt << 6;
  __shared__ float xt[64][97];
  __shared__ float wt[96*96];     // [d][o], o contiguous
  __shared__ float rr[64];
  __shared__ float rw[96];
  int tid = threadIdx.x;
  for (int idx = tid; idx < 6144; idx += 256){ int r = idx/96, d = idx - r*96;
    xt[r][d] = x[((size_t)b*4096 + l0 + r)*96 + d]; }
  if (tid < 96) rw[tid] = rmsw[tid];
  int o0 = og*96;
  for (int idx = tid; idx < 9216; idx += 256){ int o = idx%96, d = idx/96;
    wt[d*96 + o] = ipw[(size_t)(o0 + o)*96 + d]; }
  __syncthreads();
  if (tid < 64){
    float s = 0.f;
    for (int d = 0; d < 96; d++){ float v = xt[tid][d]; s += v*v; }
    rr[tid] = rsqrtf(s*(1.0f/96.0f) + 1e-5f);
  }
  __syncthreads();
  for (int idx = tid; idx < 6144; idx += 256){ int r = idx/96, d = idx - r*96;
    xt[r][d] *= rr[r]*rw[d]; }
  __syncthreads();
  int l = tid & 63, grp = tid >> 6;      // grp 0..3 -> o = grp*24 + j
  float acc[24];
  #pragma unroll
  for (int j = 0; j < 24; j++) acc[j] = 0.f;
  for (int d = 0; d < 96; d++){
    float xv = xt[l][d];
    const float* wr = &wt[d*96 + grp*24];
    #pragma unroll
    for (int j = 0; j < 24; j += 4){
      float4 w4 = *(const float4*)&wr[j];
      acc[j]   += xv*w4.x; acc[j+1] += xv*w4.y;
      acc[j+2] += xv*w4.z; acc[j+3] += xv*w4.w;
    }
  }
  #pragma unroll
  for (int j = 0; j < 24; j++){
    int o = o0 + grp*24 + j;
    if (o < 192) xc[((size_t)b*192 + o)*4096 + l0 + l] = acc[j];
    else         zT[((size_t)b*192 + (o-192))*4096 + l0 + l] = acc[j];
  }
}

// ------------------------------------------------ K2: forward rfft2 (ortho)
__global__ __launch_bounds__(256) void k_dft_fwd(const float* __restrict__ xc,
    float* __restrict__ fre, float* __restrict__ fim, float* __restrict__ fab){
  int plane = blockIdx.x;
  const float* X = xc + (size_t)plane*4096;
  __shared__ float sx[4096];
  __shared__ float t1r[2112], t1i[2112];
  __shared__ float ct[64], st[64];
  int tid = threadIdx.x;
  for (int i = tid; i < 4096; i += 256) sx[i] = X[i];
  if (tid < 64){ ct[tid] = cospif((float)tid/32.0f); st[tid] = sinpif((float)tid/32.0f); }
  __syncthreads();
  for (int idx = tid; idx < 2112; idx += 256){
    int h = idx/33, k = idx - h*33;
    float sr = 0.f, si = 0.f;
    for (int w = 0; w < 64; w++){
      int t = (w*k) & 63; float v = sx[h*64 + w];
      sr += v*ct[t]; si -= v*st[t];
    }
    t1r[idx] = sr; t1i[idx] = si;
  }
  __syncthreads();
  for (int idx = tid; idx < 2112; idx += 256){
    int f = idx/33, k = idx - f*33;
    float sr = 0.f, si = 0.f;
    for (int h = 0; h < 64; h++){
      int t = (h*f) & 63; float c = ct[t], s = st[t];
      float ar = t1r[h*33 + k], ai = t1i[h*33 + k];
      sr += ar*c + ai*s;
      si += ai*c - ar*s;
    }
    sr *= (1.0f/64.0f); si *= (1.0f/64.0f);
    size_t o = (size_t)plane*2112 + idx;
    fre[o] = sr; fim[o] = si; fab[o] = sqrtf(sr*sr + si*si);
  }
}

// ------------------------------------------------ K3: m = gelu(W1 @ |xf| + b1)   8 o per thread
// grid: b(4) x og(24) x pt(9)
__global__ __launch_bounds__(256) void k_cmix1(const float* __restrict__ fab,
    const float* __restrict__ w1, const float* __restrict__ b1, float* __restrict__ m){
  int bid = blockIdx.x;
  int pt = bid % 9; int og = (bid/9) % 24; int b = bid/216;
  int tid = threadIdx.x;
  int p = pt*256 + tid; bool act = p < 2112;
  __shared__ float wl[192*8];
  for (int idx = tid; idx < 1536; idx += 256){ int o = idx & 7, c = idx >> 3;
    wl[c*8 + o] = w1[(size_t)(og*8 + o)*192 + c]; }
  __syncthreads();
  float acc[8];
  #pragma unroll
  for (int o = 0; o < 8; o++) acc[o] = b1[og*8 + o];
  const float* xb = fab + (size_t)b*CI*2112 + p;
  for (int c = 0; c < 192; c++){
    float xv = act ? xb[(size_t)c*2112] : 0.f;
    float4 wa = *(const float4*)&wl[c*8];
    float4 wb4 = *(const float4*)&wl[c*8 + 4];
    acc[0] += xv*wa.x;  acc[1] += xv*wa.y;  acc[2] += xv*wa.z;  acc[3] += xv*wa.w;
    acc[4] += xv*wb4.x; acc[5] += xv*wb4.y; acc[6] += xv*wb4.z; acc[7] += xv*wb4.w;
  }
  if (act){
    #pragma unroll
    for (int o = 0; o < 8; o++){
      float a = acc[o];
      m[((size_t)b*192 + og*8 + o)*2112 + p] = 0.5f*a*(1.0f + erff(a*0.70710678118654752f));
    }
  }
}

// ------------------------------------------------ K4: mag = W2 @ m + b2; in-place mag*e^{i angle}
__global__ __launch_bounds__(256) void k_cmix2(const float* __restrict__ m,
    const float* __restrict__ w2, const float* __restrict__ bi2,
    float* __restrict__ fre, float* __restrict__ fim, const float* __restrict__ fab){
  int bid = blockIdx.x;
  int pt = bid % 9; int og = (bid/9) % 24; int b = bid/216;
  int tid = threadIdx.x;
  int p = pt*256 + tid; bool act = p < 2112;
  __shared__ float wl[192*8];
  for (int idx = tid; idx < 1536; idx += 256){ int o = idx & 7, c = idx >> 3;
    wl[c*8 + o] = w2[(size_t)(og*8 + o)*192 + c]; }
  __syncthreads();
  float acc[8];
  #pragma unroll
  for (int o = 0; o < 8; o++) acc[o] = bi2[og*8 + o];
  const float* xb = m + (size_t)b*CI*2112 + p;
  for (int c = 0; c < 192; c++){
    float xv = act ? xb[(size_t)c*2112] : 0.f;
    float4 wa = *(const float4*)&wl[c*8];
    float4 wb4 = *(const float4*)&wl[c*8 + 4];
    acc[0] += xv*wa.x;  acc[1] += xv*wa.y;  acc[2] += xv*wa.z;  acc[3] += xv*wa.w;
    acc[4] += xv*wb4.x; acc[5] += xv*wb4.y; acc[6] += xv*wb4.z; acc[7] += xv*wb4.w;
  }
  if (act){
    #pragma unroll
    for (int o = 0; o < 8; o++){
      size_t id = ((size_t)b*192 + og*8 + o)*2112 + p;
      float ab = fab[id];
      float re, im;
      if (ab > 1e-30f){ float sc = acc[o]/ab; re = sc*fre[id]; im = sc*fim[id]; }
      else { re = acc[o]; im = 0.f; }
      fre[id] = re; fim[id] = im;
    }
  }
}

// ------------------------------------------------ K5: Haar DWT
__global__ __launch_bounds__(256) void k_dwt(const float* __restrict__ xc,
    float* __restrict__ ll, float* __restrict__ lh, float* __restrict__ hl, float* __restrict__ hh){
  int id = blockIdx.x*256 + threadIdx.x;
  int x2 = id & 31; int y2 = (id >> 5) & 31; size_t plane = (size_t)(id >> 10);
  const float* p = xc + plane*4096;
  int h = y2 << 1, w = x2 << 1;
  float a_ = p[h*64 + w],     b_ = p[h*64 + w + 1];
  float c_ = p[(h+1)*64 + w], d_ = p[(h+1)*64 + w + 1];
  ll[id] = (a_+b_+c_+d_)*0.5f; lh[id] = (a_-b_+c_-d_)*0.5f;
  hl[id] = (a_+b_-c_-d_)*0.5f; hh[id] = (a_-b_-c_+d_)*0.5f;
}

// ------------------------------------------------ K6: full 3x3 conv on (lh,hl,hh)
// grid 864: og(12: 16 oc) x b(4) x t(3) x half(2) x cs(3: 64 ic); 3 partial buffers
__global__ __launch_bounds__(256) void k_wconv(const float* __restrict__ in,
    const float* __restrict__ ww, float* __restrict__ wpart){
  int bid = blockIdx.x;
  int og = bid % 12; int b = (bid/12) & 3; int t = (bid/48) % 3;
  int half = (bid/144) & 1; int cs = bid/288;
  int o0 = og*16, c0 = cs*64;
  const float* inb = in + (size_t)t*786432 + (size_t)b*196608;
  float* outb = wpart + (size_t)cs*2359296 + (size_t)t*786432 + (size_t)b*196608;
  __shared__ float wl[64*144];     // [icl][q][oc16]
  __shared__ float pl[2][576];     // 18 rows x 32 cols
  int tid = threadIdx.x;
  for (int idx = tid; idx < 9216; idx += 256){
    int ocl = idx & 15; int q = (idx >> 4) % 9; int icl = idx/144;
    wl[icl*144 + q*16 + ocl] = ww[((size_t)(o0 + ocl)*192 + c0 + icl)*9 + q];
  }
  int y0 = half*16;
  int x = tid & 31, yrow = tid >> 5;          // yrow 0..7
  // stage channel 0
  for (int idx = tid; idx < 576; idx += 256){
    int row = idx >> 5, col = idx & 31;
    int yg = y0 - 1 + row;
    pl[0][idx] = (yg >= 0 && yg < 32) ? inb[(size_t)c0*1024 + yg*32 + col] : 0.f;
  }
  __syncthreads();
  float acc[2][16];
  #pragma unroll
  for (int px = 0; px < 2; px++)
    #pragma unroll
    for (int o = 0; o < 16; o++) acc[px][o] = 0.f;
  int cur = 0;
  for (int icl = 0; icl < 64; icl++){
    // prefetch next channel into regs
    float pf[3] = {0.f, 0.f, 0.f};
    if (icl + 1 < 64){
      int cnext = c0 + icl + 1;
      #pragma unroll
      for (int s = 0; s < 3; s++){
        int idx = tid + s*256;
        if (idx < 576){
          int row = idx >> 5, col = idx & 31;
          int yg = y0 - 1 + row;
          pf[s] = (yg >= 0 && yg < 32) ? inb[(size_t)cnext*1024 + yg*32 + col] : 0.f;
        }
      }
    }
    // compute from pl[cur]
    const float* wbase = &wl[icl*144];
    #pragma unroll
    for (int q = 0; q < 9; q++){
      int ky = q/3, kx = q%3;
      int xx = x + kx - 1;
      bool okx = (xx >= 0 && xx < 32);
      float v0 = okx ? pl[cur][(yrow + ky)*32 + xx] : 0.f;
      float v1 = okx ? pl[cur][(yrow + 8 + ky)*32 + xx] : 0.f;
      const float4* wq = (const float4*)&wbase[q*16];
      float4 wA = wq[0], wB = wq[1], wC = wq[2], wD = wq[3];
      acc[0][0] += v0*wA.x; acc[0][1] += v0*wA.y; acc[0][2] += v0*wA.z; acc[0][3] += v0*wA.w;
      acc[0][4] += v0*wB.x; acc[0][5] += v0*wB.y; acc[0][6] += v0*wB.z; acc[0][7] += v0*wB.w;
      acc[0][8] += v0*wC.x; acc[0][9] += v0*wC.y; acc[0][10]+= v0*wC.z; acc[0][11]+= v0*wC.w;
      acc[0][12]+= v0*wD.x; acc[0][13]+= v0*wD.y; acc[0][14]+= v0*wD.z; acc[0][15]+= v0*wD.w;
      acc[1][0] += v1*wA.x; acc[1][1] += v1*wA.y; acc[1][2] += v1*wA.z; acc[1][3] += v1*wA.w;
      acc[1][4] += v1*wB.x; acc[1][5] += v1*wB.y; acc[1][6] += v1*wB.z; acc[1][7] += v1*wB.w;
      acc[1][8] += v1*wC.x; acc[1][9] += v1*wC.y; acc[1][10]+= v1*wC.z; acc[1][11]+= v1*wC.w;
      acc[1][12]+= v1*wD.x; acc[1][13]+= v1*wD.y; acc[1][14]+= v1*wD.z; acc[1][15]+= v1*wD.w;
    }
    // write prefetched channel
    if (icl + 1 < 64){
      #pragma unroll
      for (int s = 0; s < 3; s++){
        int idx = tid + s*256;
        if (idx < 576) pl[cur ^ 1][idx] = pf[s];
      }
    }
    __syncthreads();
    cur ^= 1;
  }
  int r1 = y0 + yrow;
  #pragma unroll
  for (int o = 0; o < 16; o++){
    outb[(size_t)(o0 + o)*1024 + r1*32 + x]       = acc[0][o];
    outb[(size_t)(o0 + o)*1024 + (r1+8)*32 + x]   = acc[1][o];
  }
}

// ------------------------------------------------ K7: xc = 2*xc + idwt(ll, conv(3 partials)+bias)
__global__ __launch_bounds__(256) void k_fcomb(float* __restrict__ xc,
    const float* __restrict__ ll, const float* __restrict__ wpart,
    const float* __restrict__ wb){
  int id = blockIdx.x*256 + threadIdx.x;
  int p = id & 4095; size_t plane = (size_t)(id >> 12);
  int c = (int)(plane % 192);
  int h = p >> 6, w = p & 63;
  size_t q = plane*1024 + (size_t)(h >> 1)*32 + (w >> 1);
  float bia = wb[c];
  float LLv = ll[q];
  float LH = wpart[q]             + wpart[2359296 + q]             + wpart[4718592 + q]             + bia;
  float HL = wpart[786432 + q]    + wpart[2359296 + 786432 + q]    + wpart[4718592 + 786432 + q]    + bia;
  float HH = wpart[1572864 + q]   + wpart[2359296 + 1572864 + q]   + wpart[4718592 + 1572864 + q]   + bia;
  float v;
  bool hb = (h & 1), wbit = (w & 1);
  if (!hb && !wbit)      v = (LLv + LH + HL + HH)*0.5f;
  else if (!hb && wbit)  v = (LLv - LH + HL - HH)*0.5f;
  else if (hb && !wbit)  v = (LLv + LH - HL - HH)*0.5f;
  else                   v = (LLv - LH - HL + HH)*0.5f;
  xc[id] = 2.0f*xc[id] + v;
}

// ------------------------------------------------ K8: irfft2 (ortho), accumulate into xc
__global__ __launch_bounds__(256) void k_dft_inv(const float* __restrict__ fre2,
    const float* __restrict__ fim2, float* __restrict__ xc){
  int plane = blockIdx.x;
  __shared__ float gr[2112], gi[2112], ur[2112], ui[2112];
  __shared__ float ct[64], st[64];
  int tid = threadIdx.x;
  for (int i = tid; i < 2112; i += 256){
    size_t o = (size_t)plane*2112 + i;
    gr[i] = fre2[o]; gi[i] = fim2[o];
  }
  if (tid < 64){ ct[tid] = cospif((float)tid/32.0f); st[tid] = sinpif((float)tid/32.0f); }
  __syncthreads();
  for (int idx = tid; idx < 2112; idx += 256){
    int h = idx/33, k = idx - h*33;
    float sr = 0.f, si = 0.f;
    for (int f = 0; f < 64; f++){
      int t = (f*h) & 63; float c = ct[t], s = st[t];
      float ar = gr[f*33 + k], ai = gi[f*33 + k];
      sr += ar*c - ai*s;
      si += ai*c + ar*s;
    }
    ur[idx] = sr; ui[idx] = si;
  }
  __syncthreads();
  for (int p = tid; p < 4096; p += 256){
    int h = p >> 6, w = p & 63;
    float acc = 0.f;
    for (int k = 0; k <= 32; k++){
      int t = (k*w) & 63;
      float re = ur[h*33 + k]*ct[t] - ui[h*33 + k]*st[t];
      acc += (k == 0 || k == 32) ? re : 2.0f*re;
    }
    xc[(size_t)plane*4096 + p] += acc*(1.0f/64.0f);
  }
}

// ------------------------------------------------ K9: depthwise 3x3 + SiLU -> ab
__global__ __launch_bounds__(256) void k_dwconv(const float* __restrict__ xc2,
    const float* __restrict__ dww, const float* __restrict__ dwb, float* __restrict__ ab){
  int id = blockIdx.x*256 + threadIdx.x;
  int p = id & 4095; size_t plane = (size_t)(id >> 12); int c = (int)(plane % 192);
  int h = p >> 6, w = p & 63;
  const float* pp = xc2 + plane*4096;
  float acc = dwb[c];
  #pragma unroll
  for (int ky = 0; ky < 3; ky++){
    int yy = h + ky - 1; if (yy < 0 || yy > 63) continue;
    #pragma unroll
    for (int kx = 0; kx < 3; kx++){
      int xx = w + kx - 1; if (xx < 0 || xx > 63) continue;
      acc += pp[yy*64 + xx]*dww[c*9 + ky*3 + kx];
    }
  }
  ab[id] = acc / (1.f + expf(-acc));
}

// ------------------------------------------------ K10: x_proj; emit Bs, Cs, dts(rank6)
__global__ __launch_bounds__(256) void k_xproj(const float* __restrict__ ab,
    const float* __restrict__ xpw,
    float* __restrict__ Bsb, float* __restrict__ Csb, float* __restrict__ dlsb){
  int bid = blockIdx.x;                 // (b*4+k)*64 + s
  int s = bid & 63; int k = (bid >> 6) & 3; int b = bid >> 8;
  int tid = threadIdx.x;
  __shared__ float als[192][65];
  __shared__ float dls[6][64];
  int l0 = s << 6;
  for (int idx = tid; idx < 192*64; idx += 256){
    int d = idx >> 6, i = idx & 63;
    int pl;
    if (k == 0)      pl = l0 + i;
    else if (k == 1) pl = (i << 6) + s;
    else if (k == 2) pl = 4095 - (l0 + i);
    else             pl = 4095 - ((i << 6) + s);
    als[d][i] = ab[((size_t)b*192 + d)*4096 + pl];
  }
  __syncthreads();
  for (int j = tid; j < 38*64; j += 256){
    int cp = j >> 6, i = j & 63;
    const float* wr = xpw + ((size_t)k*38 + cp)*192;
    float acc = 0.f;
    #pragma unroll 4
    for (int d = 0; d < 192; d++) acc += als[d][i]*wr[d];
    if (cp < 6) dls[cp][i] = acc;
    else if (cp < 22) Bsb[((size_t)(b*4 + k)*16 + (cp - 6 ))*4096 + l0 + i] = acc;
    else              Csb[((size_t)(b*4 + k)*16 + (cp - 22))*4096 + l0 + i] = acc;
  }
  __syncthreads();
  size_t dbase = (size_t)((b*4 + k)*64 + s)*384;
  for (int j = tid; j < 384; j += 256){
    int i = j/6, r = j - i*6;
    dlsb[dbase + j] = dls[r][i];
  }
}

// ------------------------------------------------ K11: scan phase A — per-segment (P,Q)
__global__ __launch_bounds__(192) void k_scanA(const float* __restrict__ ab,
    const float* __restrict__ dlsb, const float* __restrict__ Bsb,
    const float* __restrict__ dtw, const float* __restrict__ dtb,
    const float* __restrict__ alog, float* __restrict__ Pb, float* __restrict__ Qb){
  int bid = blockIdx.x; int s = bid & 63; int k = (bid >> 6) & 3; int b = bid >> 8;
  int c = threadIdx.x; int bk = b*4 + k;
  __shared__ float sdl[384];
  __shared__ float sB[16][64];
  size_t dbase = (size_t)(bk*64 + s)*384;
  for (int j = c; j < 384; j += 192) sdl[j] = dlsb[dbase + j];
  for (int j = c; j < 1024; j += 192){ int n = j >> 6, i = j & 63;
    sB[n][i] = Bsb[((size_t)bk*16 + n)*4096 + (s << 6) + i]; }
  __syncthreads();
  float A[16], P[16], Q[16];
  const float* arow = alog + ((size_t)k*192 + c)*16;
  #pragma unroll
  for (int n = 0; n < 16; n++){ A[n] = -expf(arow[n]); P[n] = 1.f; Q[n] = 0.f; }
  float dw[6];
  #pragma unroll
  for (int r = 0; r < 6; r++) dw[r] = dtw[((size_t)k*192 + c)*6 + r];
  float db = dtb[k*192 + c];
  const float* abp = ab + ((size_t)b*192 + c)*4096;
  int p0, pst;
  if (k == 0){ p0 = s << 6;        pst = 1;  }
  else if (k == 1){ p0 = s;        pst = 64; }
  else if (k == 2){ p0 = 4095 - (s << 6); pst = -1; }
  else { p0 = 4095 - s;            pst = -64; }
  for (int i = 0; i < 64; i++){
    float u = abp[p0 + pst*i];
    float acc = db;
    #pragma unroll
    for (int r = 0; r < 6; r++) acc += sdl[i*6 + r]*dw[r];
    float dl = fmaxf(acc, 0.f) + log1pf(expf(-fabsf(acc)));
    float du = dl*u;
    #pragma unroll
    for (int n = 0; n < 16; n++){
      float e = expf(dl*A[n]);
      P[n] *= e;
      Q[n] = Q[n]*e + du*sB[n][i];
    }
  }
  size_t pbase = ((size_t)(bk*64 + s)*16)*192 + c;
  #pragma unroll
  for (int n = 0; n < 16; n++){ Pb[pbase + (size_t)n*192] = P[n]; Qb[pbase + (size_t)n*192] = Q[n]; }
}

// ------------------------------------------------ K12: scan phase B — prefix over 64 segments
__global__ __launch_bounds__(256) void k_scanB(const float* __restrict__ Pb,
    const float* __restrict__ Qb, float* __restrict__ hinb){
  int id = blockIdx.x*256 + threadIdx.x;   // (bk*16+n)*192+c -> 49152
  int c = id % 192; int rest = id / 192; int n = rest % 16; int bk = rest / 16;
  float h = 0.f;
  for (int s = 0; s < 64; s++){
    size_t o = (((size_t)bk*64 + s)*16 + n)*192 + c;
    hinb[o] = h;
    h = Pb[o]*h + Qb[o];
  }
}

// ------------------------------------------------ K13: scan phase C — replay, scatter-add into yb
__global__ __launch_bounds__(192) void k_scanC(const float* __restrict__ ab,
    const float* __restrict__ dlsb, const float* __restrict__ Bsb, const float* __restrict__ Csb,
    const float* __restrict__ hinb, const float* __restrict__ dtw, const float* __restrict__ dtb,
    const float* __restrict__ alog, const float* __restrict__ Dsp, float* __restrict__ yb){
  int bid = blockIdx.x; int s = bid & 63; int k = (bid >> 6) & 3; int b = bid >> 8;
  int c = threadIdx.x; int bk = b*4 + k;
  __shared__ float sdl[384];
  __shared__ float sB[16][64];
  __shared__ float sC[16][64];
  size_t dbase = (size_t)(bk*64 + s)*384;
  for (int j = c; j < 384; j += 192) sdl[j] = dlsb[dbase + j];
  for (int j = c; j < 1024; j += 192){ int n = j >> 6, i = j & 63;
    size_t o = ((size_t)bk*16 + n)*4096 + (s << 6) + i;
    sB[n][i] = Bsb[o]; sC[n][i] = Csb[o]; }
  __syncthreads();
  float A[16], h[16];
  const float* arow = alog + ((size_t)k*192 + c)*16;
  #pragma unroll
  for (int n = 0; n < 16; n++) A[n] = -expf(arow[n]);
  size_t hbase = ((size_t)(bk*64 + s)*16)*192 + c;
  #pragma unroll
  for (int n = 0; n < 16; n++) h[n] = hinb[hbase + (size_t)n*192];
  float dw[6];
  #pragma unroll
  for (int r = 0; r < 6; r++) dw[r] = dtw[((size_t)k*192 + c)*6 + r];
  float db = dtb[k*192 + c];
  float Dc = Dsp[k*192 + c];
  const float* abp = ab + ((size_t)b*192 + c)*4096;
  int p0, pst;
  if (k == 0){ p0 = s << 6;        pst = 1;  }
  else if (k == 1){ p0 = s;        pst = 64; }
  else if (k == 2){ p0 = 4095 - (s << 6); pst = -1; }
  else { p0 = 4095 - s;            pst = -64; }
  for (int i = 0; i < 64; i++){
    int pl = p0 + pst*i;
    float u = abp[pl];
    float acc = db;
    #pragma unroll
    for (int r = 0; r < 6; r++) acc += sdl[i*6 + r]*dw[r];
    float dl = fmaxf(acc, 0.f) + log1pf(expf(-fabsf(acc)));
    float du = dl*u;
    float y = 0.f;
    #pragma unroll
    for (int n = 0; n < 16; n++){
      float e = expf(dl*A[n]);
      h[n] = h[n]*e + du*sB[n][i];
      y += h[n]*sC[n][i];
    }
    y += u*Dc;
    atomicAdd(&yb[((size_t)b*4096 + pl)*192 + c], y);
  }
}

// ------------------------------------------------ K14: symmetry enhance
__global__ __launch_bounds__(256) void k_enh(const float* __restrict__ yb,
    const float* __restrict__ symw, float* __restrict__ yfb){
  int id = blockIdx.x*256 + threadIdx.x;
  int c = id % 192; int rest = id / 192; int l = rest & 4095; int b = rest >> 12;
  int w = l & 63; int lr = (l | 63) - w;
  float v  = yb[id];
  float vr = yb[(((size_t)b << 12) + lr)*192 + c];
  float wg = 1.f/(1.f + expf(-symw[0]));
  float enh = v*(1.f - wg) + 0.5f*(v + vr)*wg;
  yfb[id] = v + 0.2f*enh;
}

// ------------------------------------------------ K15: LayerNorm + SiLU(z) + out_proj + residual (tiled)
// grid: b(4) x lt(128: 32 l each) x og(2: 48 o each) = 1024
__global__ __launch_bounds__(256) void k_final(const float* __restrict__ yf,
    const float* __restrict__ zT, const float* __restrict__ g, const float* __restrict__ bta,
    const float* __restrict__ opw, const float* __restrict__ x, float* __restrict__ out){
  int og = blockIdx.x & 1; int lt = (blockIdx.x >> 1) & 127; int b = blockIdx.x >> 8;
  int l0 = lt << 5;
  __shared__ float sv[32][193];
  __shared__ float wt[192*48];      // [c][o48]
  __shared__ float sg[192], sb2[192];
  __shared__ float smu[32], srs[32];
  int tid = threadIdx.x;
  for (int idx = tid; idx < 6144; idx += 256){ int r = idx/192, c = idx - r*192;
    sv[r][c] = yf[((size_t)b*4096 + l0 + r)*192 + c]; }
  if (tid < 192){ sg[tid] = g[tid]; sb2[tid] = bta[tid]; }
  int o0 = og*48;
  for (int idx = tid; idx < 9216; idx += 256){ int o = idx % 48, c = idx/48;
    wt[c*48 + o] = opw[(size_t)(o0 + o)*192 + c]; }
  __syncthreads();
  if (tid < 32){
    float s1 = 0.f, s2 = 0.f;
    for (int c = 0; c < 192; c++){ float v = sv[tid][c]; s1 += v; s2 += v*v; }
    float mu = s1*(1.0f/192.0f);
    smu[tid] = mu; srs[tid] = rsqrtf(s2*(1.0f/192.0f) - mu*mu + 1e-5f);
  }
  __syncthreads();
  for (int idx = tid; idx < 6144; idx += 256){ int l = idx & 31, c = idx >> 5;
    float zv = zT[((size_t)b*192 + c)*4096 + l0 + l];
    float v = sv[l][c];
    float yn = (v - smu[l])*srs[l]*sg[c] + sb2[c];
    sv[l][c] = yn * (zv/(1.f + expf(-zv)));
  }
  __syncthreads();
  int l = tid & 31, grp = tid >> 5;       // grp 0..7, o = grp*6 + j
  float acc[6];
  #pragma unroll
  for (int j = 0; j < 6; j++) acc[j] = 0.f;
  for (int c = 0; c < 192; c++){
    float svv = sv[l][c];
    const float* wr = &wt[c*48 + grp*6];
    #pragma unroll
    for (int j = 0; j < 6; j += 2){
      float2 w2 = *(const float2*)&wr[j];
      acc[j]   += svv*w2.x; acc[j+1] += svv*w2.y;
    }
  }
  size_t ob = ((size_t)b*4096 + l0 + l)*96 + o0 + grp*6;
  #pragma unroll
  for (int j = 0; j < 6; j++) acc[j] += x[ob + j];
  #pragma unroll
  for (int j = 0; j < 6; j += 2){
    float2 v2; v2.x = acc[j]; v2.y = acc[j+1];
    *(float2*)&out[ob + j] = v2;
  }
}

// ================================================================ host
extern "C" void kernel_launch(void* const* d_in, const int* in_sizes, int n_in,
                              void* d_out, int out_size, void* d_ws, size_t ws_size,
                              hipStream_t stream){
  (void)in_sizes; (void)n_in; (void)out_size; (void)ws_size;
  const float* ix   = (const float*)d_in[0];
  const float* ipw  = (const float*)d_in[1];
  const float* fw1  = (const float*)d_in[2];
  const float* fb1  = (const float*)d_in[3];
  const float* fw2  = (const float*)d_in[4];
  const float* fb2  = (const float*)d_in[5];
  const float* ww   = (const float*)d_in[6];
  const float* wb   = (const float*)d_in[7];
  const float* dww  = (const float*)d_in[8];
  const float* dwb  = (const float*)d_in[9];
  const float* symw = (const float*)d_in[10];
  const float* xpw  = (const float*)d_in[11];
  const float* dtw  = (const float*)d_in[12];
  const float* dtb  = (const float*)d_in[13];
  const float* alog = (const float*)d_in[14];
  const float* Dsp  = (const float*)d_in[15];
  const float* ong  = (const float*)d_in[16];
  const float* onb  = (const float*)d_in[17];
  const float* opw  = (const float*)d_in[18];
  const float* rmsw = (const float*)d_in[19];

  float* W = (float*)d_ws;
  const size_t SZ_BLC = 3145728, SZ_F = 1622016, SZ_H = 786432;
  float* zT  = W;                   // [b][192][4096]
  float* ab  = zT + SZ_BLC;
  float* R0  = ab + SZ_BLC;
  // phase 1
  float* xc    = R0;
  float* fre   = xc  + SZ_BLC;
  float* fim   = fre + SZ_F;
  float* fab   = fim + SZ_F;
  float* mb    = fab + SZ_F;
  float* llb   = mb  + SZ_F;
  float* lhb   = llb + SZ_H;        // lh,hl,hh consecutive
  float* wpart = lhb + 3*SZ_H;      // 3 partial buffers x 2,359,296
  // phase 2 (after dwconv, xc & friends dead)
  float* Bsb  = R0;
  float* Csb  = Bsb + 1048576;
  float* dlsb = Csb + 1048576;
  float* Pb   = dlsb + 393216;
  float* Qb   = Pb + SZ_BLC;
  float* hinb = Qb + SZ_BLC;
  float* yb   = hinb + SZ_BLC;
  float* yfb  = yb + SZ_BLC;

  hipLaunchKernelGGL(k_rms_inproj, dim3(1024),   dim3(256), 0, stream, ix, rmsw, ipw, xc, zT);
  hipLaunchKernelGGL(k_dft_fwd,    dim3(4*192),  dim3(256), 0, stream, xc, fre, fim, fab);
  hipLaunchKernelGGL(k_cmix1,      dim3(864),    dim3(256), 0, stream, fab, fw1, fb1, mb);
  hipLaunchKernelGGL(k_cmix2,      dim3(864),    dim3(256), 0, stream, mb, fw2, fb2, fre, fim, fab);
  hipLaunchKernelGGL(k_dwt,        dim3(3072),   dim3(256), 0, stream, xc, llb, lhb, lhb + SZ_H, lhb + 2*SZ_H);
  hipLaunchKernelGGL(k_wconv,      dim3(864),    dim3(256), 0, stream, lhb, ww, wpart);
  hipLaunchKernelGGL(k_fcomb,      dim3(12288),  dim3(256), 0, stream, xc, llb, wpart, wb);
  hipLaunchKernelGGL(k_dft_inv,    dim3(4*192),  dim3(256), 0, stream, fre, fim, xc);
  hipLaunchKernelGGL(k_dwconv,     dim3(12288),  dim3(256), 0, stream, xc, dww, dwb, ab);
  hipLaunchKernelGGL(k_xproj,      dim3(1024),   dim3(256), 0, stream, ab, xpw, Bsb, Csb, dlsb);
  hipLaunchKernelGGL(k_scanA,      dim3(1024),   dim3(192), 0, stream, ab, dlsb, Bsb, dtw, dtb, alog, Pb, Qb);
  hipLaunchKernelGGL(k_scanB,      dim3(192),    dim3(256), 0, stream, Pb, Qb, hinb);
  hipLaunchKernelGGL(k_zero,       dim3(12288),  dim3(256), 0, stream, yb, (int)SZ_BLC);
  hipLaunchKernelGGL(k_scanC,      dim3(1024),   dim3(192), 0, stream, ab, dlsb, Bsb, Csb, hinb, dtw, dtb, alog, Dsp, yb);
  hipLaunchKernelGGL(k_enh,        dim3(12288),  dim3(256), 0, stream, yb, symw, yfb);
  hipLaunchKernelGGL(k_final,      dim3(1024),   dim3(256), 0, stream, yfb, zT, ong, onb, opw, ix, (float*)d_out);
}

// Round 5
// 933.519 us; speedup vs baseline: 2.1436x; 1.1614x over previous
//
#include <hip/hip_runtime.h>
#include <hip/hip_bf16.h>

#define CI 192
#define LL_ 4096

__global__ __launch_bounds__(256) void k_zero(float* __restrict__ p, int n){
  int i = blockIdx.x*256 + threadIdx.x;
  if (i < n) p[i] = 0.f;
}

// ------------------------------------------------ K1: RMSNorm + in_proj (tiled GEMM, 48-o tiles)
// grid: b(4) x lt(64) x og(8)
__global__ __launch_bounds__(256) void k_rms_inproj(const float* __restrict__ x,
    const float* __restrict__ rmsw, const float* __restrict__ ipw,
    float* __restrict__ xc, float* __restrict__ zT){
  int og = blockIdx.x & 7; int lt = (blockIdx.x >> 3) & 63; int b = blockIdx.x >> 9;
  int l0 = lt << 6;
  __shared__ float xt[64][97];
  __shared__ float wt[96*48];     // [d][o48]
  __shared__ float rr[64];
  __shared__ float rw[96];
  int tid = threadIdx.x;
  for (int idx = tid; idx < 6144; idx += 256){ int r = idx/96, d = idx - r*96;
    xt[r][d] = x[((size_t)b*4096 + l0 + r)*96 + d]; }
  if (tid < 96) rw[tid] = rmsw[tid];
  int o0 = og*48;
  for (int idx = tid; idx < 4608; idx += 256){ int o = idx%48, d = idx/48;
    wt[d*48 + o] = ipw[(size_t)(o0 + o)*96 + d]; }
  __syncthreads();
  if (tid < 64){
    float s = 0.f;
    for (int d = 0; d < 96; d++){ float v = xt[tid][d]; s += v*v; }
    rr[tid] = rsqrtf(s*(1.0f/96.0f) + 1e-5f);
  }
  __syncthreads();
  for (int idx = tid; idx < 6144; idx += 256){ int r = idx/96, d = idx - r*96;
    xt[r][d] *= rr[r]*rw[d]; }
  __syncthreads();
  int l = tid & 63, grp = tid >> 6;      // grp 0..3 -> o = o0 + grp*12 + j
  float acc[12];
  #pragma unroll
  for (int j = 0; j < 12; j++) acc[j] = 0.f;
  for (int d = 0; d < 96; d++){
    float xv = xt[l][d];
    const float* wr = &wt[d*48 + grp*12];
    #pragma unroll
    for (int j = 0; j < 12; j += 4){
      float4 w4 = *(const float4*)&wr[j];
      acc[j]   += xv*w4.x; acc[j+1] += xv*w4.y;
      acc[j+2] += xv*w4.z; acc[j+3] += xv*w4.w;
    }
  }
  #pragma unroll
  for (int j = 0; j < 12; j++){
    int o = o0 + grp*12 + j;
    if (o < 192) xc[((size_t)b*192 + o)*4096 + l0 + l] = acc[j];
    else         zT[((size_t)b*192 + (o-192))*4096 + l0 + l] = acc[j];
  }
}

// ------------------------------------------------ K2: forward rfft2 (ortho)
__global__ __launch_bounds__(256) void k_dft_fwd(const float* __restrict__ xc,
    float* __restrict__ fre, float* __restrict__ fim, float* __restrict__ fab){
  int plane = blockIdx.x;
  const float* X = xc + (size_t)plane*4096;
  __shared__ float sx[4096];
  __shared__ float t1r[2112], t1i[2112];
  __shared__ float ct[64], st[64];
  int tid = threadIdx.x;
  for (int i = tid; i < 4096; i += 256) sx[i] = X[i];
  if (tid < 64){ ct[tid] = cospif((float)tid/32.0f); st[tid] = sinpif((float)tid/32.0f); }
  __syncthreads();
  for (int idx = tid; idx < 2112; idx += 256){
    int h = idx/33, k = idx - h*33;
    float sr = 0.f, si = 0.f;
    for (int w = 0; w < 64; w++){
      int t = (w*k) & 63; float v = sx[h*64 + w];
      sr += v*ct[t]; si -= v*st[t];
    }
    t1r[idx] = sr; t1i[idx] = si;
  }
  __syncthreads();
  for (int idx = tid; idx < 2112; idx += 256){
    int f = idx/33, k = idx - f*33;
    float sr = 0.f, si = 0.f;
    for (int h = 0; h < 64; h++){
      int t = (h*f) & 63; float c = ct[t], s = st[t];
      float ar = t1r[h*33 + k], ai = t1i[h*33 + k];
      sr += ar*c + ai*s;
      si += ai*c - ar*s;
    }
    sr *= (1.0f/64.0f); si *= (1.0f/64.0f);
    size_t o = (size_t)plane*2112 + idx;
    fre[o] = sr; fim[o] = si; fab[o] = sqrtf(sr*sr + si*si);
  }
}

// ------------------------------------------------ K3: m = gelu(W1 @ |xf| + b1)
__global__ __launch_bounds__(256) void k_cmix1(const float* __restrict__ fab,
    const float* __restrict__ w1, const float* __restrict__ b1, float* __restrict__ m){
  int bid = blockIdx.x;
  int pt = bid % 9; int og = (bid/9) % 24; int b = bid/216;
  int tid = threadIdx.x;
  int p = pt*256 + tid; bool act = p < 2112;
  __shared__ float wl[192*8];
  for (int idx = tid; idx < 1536; idx += 256){ int o = idx & 7, c = idx >> 3;
    wl[c*8 + o] = w1[(size_t)(og*8 + o)*192 + c]; }
  __syncthreads();
  float acc[8];
  #pragma unroll
  for (int o = 0; o < 8; o++) acc[o] = b1[og*8 + o];
  const float* xb = fab + (size_t)b*CI*2112 + p;
  for (int c = 0; c < 192; c++){
    float xv = act ? xb[(size_t)c*2112] : 0.f;
    float4 wa = *(const float4*)&wl[c*8];
    float4 wb4 = *(const float4*)&wl[c*8 + 4];
    acc[0] += xv*wa.x;  acc[1] += xv*wa.y;  acc[2] += xv*wa.z;  acc[3] += xv*wa.w;
    acc[4] += xv*wb4.x; acc[5] += xv*wb4.y; acc[6] += xv*wb4.z; acc[7] += xv*wb4.w;
  }
  if (act){
    #pragma unroll
    for (int o = 0; o < 8; o++){
      float a = acc[o];
      m[((size_t)b*192 + og*8 + o)*2112 + p] = 0.5f*a*(1.0f + erff(a*0.70710678118654752f));
    }
  }
}

// ------------------------------------------------ K4: mag = W2 @ m + b2; in-place mag*e^{i angle}
__global__ __launch_bounds__(256) void k_cmix2(const float* __restrict__ m,
    const float* __restrict__ w2, const float* __restrict__ bi2,
    float* __restrict__ fre, float* __restrict__ fim, const float* __restrict__ fab){
  int bid = blockIdx.x;
  int pt = bid % 9; int og = (bid/9) % 24; int b = bid/216;
  int tid = threadIdx.x;
  int p = pt*256 + tid; bool act = p < 2112;
  __shared__ float wl[192*8];
  for (int idx = tid; idx < 1536; idx += 256){ int o = idx & 7, c = idx >> 3;
    wl[c*8 + o] = w2[(size_t)(og*8 + o)*192 + c]; }
  __syncthreads();
  float acc[8];
  #pragma unroll
  for (int o = 0; o < 8; o++) acc[o] = bi2[og*8 + o];
  const float* xb = m + (size_t)b*CI*2112 + p;
  for (int c = 0; c < 192; c++){
    float xv = act ? xb[(size_t)c*2112] : 0.f;
    float4 wa = *(const float4*)&wl[c*8];
    float4 wb4 = *(const float4*)&wl[c*8 + 4];
    acc[0] += xv*wa.x;  acc[1] += xv*wa.y;  acc[2] += xv*wa.z;  acc[3] += xv*wa.w;
    acc[4] += xv*wb4.x; acc[5] += xv*wb4.y; acc[6] += xv*wb4.z; acc[7] += xv*wb4.w;
  }
  if (act){
    #pragma unroll
    for (int o = 0; o < 8; o++){
      size_t id = ((size_t)b*192 + og*8 + o)*2112 + p;
      float ab = fab[id];
      float re, im;
      if (ab > 1e-30f){ float sc = acc[o]/ab; re = sc*fre[id]; im = sc*fim[id]; }
      else { re = acc[o]; im = 0.f; }
      fre[id] = re; fim[id] = im;
    }
  }
}

// ------------------------------------------------ K5: Haar DWT
__global__ __launch_bounds__(256) void k_dwt(const float* __restrict__ xc,
    float* __restrict__ ll, float* __restrict__ lh, float* __restrict__ hl, float* __restrict__ hh){
  int id = blockIdx.x*256 + threadIdx.x;
  int x2 = id & 31; int y2 = (id >> 5) & 31; size_t plane = (size_t)(id >> 10);
  const float* p = xc + plane*4096;
  int h = y2 << 1, w = x2 << 1;
  float a_ = p[h*64 + w],     b_ = p[h*64 + w + 1];
  float c_ = p[(h+1)*64 + w], d_ = p[(h+1)*64 + w + 1];
  ll[id] = (a_+b_+c_+d_)*0.5f; lh[id] = (a_-b_+c_-d_)*0.5f;
  hl[id] = (a_+b_-c_-d_)*0.5f; hh[id] = (a_-b_-c_+d_)*0.5f;
}

// ------------------------------------------------ K6: full 3x3 conv on (lh,hl,hh)
__global__ __launch_bounds__(256) void k_wconv(const float* __restrict__ in,
    const float* __restrict__ ww, float* __restrict__ wpart){
  int bid = blockIdx.x;
  int og = bid % 12; int b = (bid/12) & 3; int t = (bid/48) % 3;
  int half = (bid/144) & 1; int cs = bid/288;
  int o0 = og*16, c0 = cs*64;
  const float* inb = in + (size_t)t*786432 + (size_t)b*196608;
  float* outb = wpart + (size_t)cs*2359296 + (size_t)t*786432 + (size_t)b*196608;
  __shared__ float wl[64*144];
  __shared__ float pl[2][576];
  int tid = threadIdx.x;
  for (int idx = tid; idx < 9216; idx += 256){
    int ocl = idx & 15; int q = (idx >> 4) % 9; int icl = idx/144;
    wl[icl*144 + q*16 + ocl] = ww[((size_t)(o0 + ocl)*192 + c0 + icl)*9 + q];
  }
  int y0 = half*16;
  int x = tid & 31, yrow = tid >> 5;
  for (int idx = tid; idx < 576; idx += 256){
    int row = idx >> 5, col = idx & 31;
    int yg = y0 - 1 + row;
    pl[0][idx] = (yg >= 0 && yg < 32) ? inb[(size_t)c0*1024 + yg*32 + col] : 0.f;
  }
  __syncthreads();
  float acc[2][16];
  #pragma unroll
  for (int px = 0; px < 2; px++)
    #pragma unroll
    for (int o = 0; o < 16; o++) acc[px][o] = 0.f;
  int cur = 0;
  for (int icl = 0; icl < 64; icl++){
    float pf[3] = {0.f, 0.f, 0.f};
    if (icl + 1 < 64){
      int cnext = c0 + icl + 1;
      #pragma unroll
      for (int s = 0; s < 3; s++){
        int idx = tid + s*256;
        if (idx < 576){
          int row = idx >> 5, col = idx & 31;
          int yg = y0 - 1 + row;
          pf[s] = (yg >= 0 && yg < 32) ? inb[(size_t)cnext*1024 + yg*32 + col] : 0.f;
        }
      }
    }
    const float* wbase = &wl[icl*144];
    #pragma unroll
    for (int q = 0; q < 9; q++){
      int ky = q/3, kx = q%3;
      int xx = x + kx - 1;
      bool okx = (xx >= 0 && xx < 32);
      float v0 = okx ? pl[cur][(yrow + ky)*32 + xx] : 0.f;
      float v1 = okx ? pl[cur][(yrow + 8 + ky)*32 + xx] : 0.f;
      const float4* wq = (const float4*)&wbase[q*16];
      float4 wA = wq[0], wB = wq[1], wC = wq[2], wD = wq[3];
      acc[0][0] += v0*wA.x; acc[0][1] += v0*wA.y; acc[0][2] += v0*wA.z; acc[0][3] += v0*wA.w;
      acc[0][4] += v0*wB.x; acc[0][5] += v0*wB.y; acc[0][6] += v0*wB.z; acc[0][7] += v0*wB.w;
      acc[0][8] += v0*wC.x; acc[0][9] += v0*wC.y; acc[0][10]+= v0*wC.z; acc[0][11]+= v0*wC.w;
      acc[0][12]+= v0*wD.x; acc[0][13]+= v0*wD.y; acc[0][14]+= v0*wD.z; acc[0][15]+= v0*wD.w;
      acc[1][0] += v1*wA.x; acc[1][1] += v1*wA.y; acc[1][2] += v1*wA.z; acc[1][3] += v1*wA.w;
      acc[1][4] += v1*wB.x; acc[1][5] += v1*wB.y; acc[1][6] += v1*wB.z; acc[1][7] += v1*wB.w;
      acc[1][8] += v1*wC.x; acc[1][9] += v1*wC.y; acc[1][10]+= v1*wC.z; acc[1][11]+= v1*wC.w;
      acc[1][12]+= v1*wD.x; acc[1][13]+= v1*wD.y; acc[1][14]+= v1*wD.z; acc[1][15]+= v1*wD.w;
    }
    if (icl + 1 < 64){
      #pragma unroll
      for (int s = 0; s < 3; s++){
        int idx = tid + s*256;
        if (idx < 576) pl[cur ^ 1][idx] = pf[s];
      }
    }
    __syncthreads();
    cur ^= 1;
  }
  int r1 = y0 + yrow;
  #pragma unroll
  for (int o = 0; o < 16; o++){
    outb[(size_t)(o0 + o)*1024 + r1*32 + x]       = acc[0][o];
    outb[(size_t)(o0 + o)*1024 + (r1+8)*32 + x]   = acc[1][o];
  }
}

// ------------------------------------------------ K7: xc = 2*xc + idwt(ll, conv(3 partials)+bias)
__global__ __launch_bounds__(256) void k_fcomb(float* __restrict__ xc,
    const float* __restrict__ ll, const float* __restrict__ wpart,
    const float* __restrict__ wb){
  int id = blockIdx.x*256 + threadIdx.x;
  int p = id & 4095; size_t plane = (size_t)(id >> 12);
  int c = (int)(plane % 192);
  int h = p >> 6, w = p & 63;
  size_t q = plane*1024 + (size_t)(h >> 1)*32 + (w >> 1);
  float bia = wb[c];
  float LLv = ll[q];
  float LH = wpart[q]             + wpart[2359296 + q]             + wpart[4718592 + q]             + bia;
  float HL = wpart[786432 + q]    + wpart[2359296 + 786432 + q]    + wpart[4718592 + 786432 + q]    + bia;
  float HH = wpart[1572864 + q]   + wpart[2359296 + 1572864 + q]   + wpart[4718592 + 1572864 + q]   + bia;
  float v;
  bool hb = (h & 1), wbit = (w & 1);
  if (!hb && !wbit)      v = (LLv + LH + HL + HH)*0.5f;
  else if (!hb && wbit)  v = (LLv - LH + HL - HH)*0.5f;
  else if (hb && !wbit)  v = (LLv + LH - HL - HH)*0.5f;
  else                   v = (LLv - LH - HL + HH)*0.5f;
  xc[id] = 2.0f*xc[id] + v;
}

// ------------------------------------------------ K8: irfft2 (ortho), accumulate into xc
__global__ __launch_bounds__(256) void k_dft_inv(const float* __restrict__ fre2,
    const float* __restrict__ fim2, float* __restrict__ xc){
  int plane = blockIdx.x;
  __shared__ float gr[2112], gi[2112], ur[2112], ui[2112];
  __shared__ float ct[64], st[64];
  int tid = threadIdx.x;
  for (int i = tid; i < 2112; i += 256){
    size_t o = (size_t)plane*2112 + i;
    gr[i] = fre2[o]; gi[i] = fim2[o];
  }
  if (tid < 64){ ct[tid] = cospif((float)tid/32.0f); st[tid] = sinpif((float)tid/32.0f); }
  __syncthreads();
  for (int idx = tid; idx < 2112; idx += 256){
    int h = idx/33, k = idx - h*33;
    float sr = 0.f, si = 0.f;
    for (int f = 0; f < 64; f++){
      int t = (f*h) & 63; float c = ct[t], s = st[t];
      float ar = gr[f*33 + k], ai = gi[f*33 + k];
      sr += ar*c - ai*s;
      si += ai*c + ar*s;
    }
    ur[idx] = sr; ui[idx] = si;
  }
  __syncthreads();
  for (int p = tid; p < 4096; p += 256){
    int h = p >> 6, w = p & 63;
    float acc = 0.f;
    for (int k = 0; k <= 32; k++){
      int t = (k*w) & 63;
      float re = ur[h*33 + k]*ct[t] - ui[h*33 + k]*st[t];
      acc += (k == 0 || k == 32) ? re : 2.0f*re;
    }
    xc[(size_t)plane*4096 + p] += acc*(1.0f/64.0f);
  }
}

// ------------------------------------------------ K9: depthwise 3x3 + SiLU -> ab
__global__ __launch_bounds__(256) void k_dwconv(const float* __restrict__ xc2,
    const float* __restrict__ dww, const float* __restrict__ dwb, float* __restrict__ ab){
  int id = blockIdx.x*256 + threadIdx.x;
  int p = id & 4095; size_t plane = (size_t)(id >> 12); int c = (int)(plane % 192);
  int h = p >> 6, w = p & 63;
  const float* pp = xc2 + plane*4096;
  float acc = dwb[c];
  #pragma unroll
  for (int ky = 0; ky < 3; ky++){
    int yy = h + ky - 1; if (yy < 0 || yy > 63) continue;
    #pragma unroll
    for (int kx = 0; kx < 3; kx++){
      int xx = w + kx - 1; if (xx < 0 || xx > 63) continue;
      acc += pp[yy*64 + xx]*dww[c*9 + ky*3 + kx];
    }
  }
  ab[id] = acc / (1.f + __expf(-acc));
}

// ------------------------------------------------ K9b: transpose planes: aT[b][c][w*64+h] = a[b][c][h*64+w]
__global__ __launch_bounds__(256) void k_transpose(const float* __restrict__ ab, float* __restrict__ aT){
  int plane = blockIdx.x;
  __shared__ float t[64][65];
  int tid = threadIdx.x;
  const float* src = ab + (size_t)plane*4096;
  for (int idx = tid; idx < 4096; idx += 256) t[idx >> 6][idx & 63] = src[idx];
  __syncthreads();
  float* dst = aT + (size_t)plane*4096;
  for (int idx = tid; idx < 4096; idx += 256) dst[idx] = t[idx & 63][idx >> 6];
}

// ------------------------------------------------ K10: x_proj; emit Bs, Cs, dts(rank6), xs[bk][l][c]
__global__ __launch_bounds__(256) void k_xproj(const float* __restrict__ ab,
    const float* __restrict__ aT, const float* __restrict__ xpw,
    float* __restrict__ Bsb, float* __restrict__ Csb, float* __restrict__ dlsb,
    float* __restrict__ xsb){
  int bid = blockIdx.x;                 // (b*4+k)*64 + s
  int s = bid & 63; int k = (bid >> 6) & 3; int b = bid >> 8;
  int tid = threadIdx.x;
  __shared__ float als[192][65];
  __shared__ float dls[6][64];
  int l0 = s << 6;
  const float* src = (k & 1) ? aT : ab;
  int off0 = (k < 2) ? l0 : (4095 - l0);
  int stp  = (k < 2) ? 1 : -1;
  for (int idx = tid; idx < 192*64; idx += 256){
    int d = idx >> 6, i = idx & 63;
    als[d][i] = src[((size_t)b*192 + d)*4096 + off0 + stp*i];
  }
  __syncthreads();
  for (int j = tid; j < 38*64; j += 256){
    int cp = j >> 6, i = j & 63;
    const float* wr = xpw + ((size_t)k*38 + cp)*192;
    float acc = 0.f;
    #pragma unroll 4
    for (int d = 0; d < 192; d++) acc += als[d][i]*wr[d];
    if (cp < 6) dls[cp][i] = acc;
    else if (cp < 22) Bsb[((size_t)(b*4 + k)*16 + (cp - 6 ))*4096 + l0 + i] = acc;
    else              Csb[((size_t)(b*4 + k)*16 + (cp - 22))*4096 + l0 + i] = acc;
  }
  // xs passthrough, coalesced [bk][l][c]
  size_t xbase = ((size_t)(b*4 + k)*4096 + l0)*192;
  for (int j = tid; j < 192*64; j += 256){
    int i = j / 192, c = j % 192;
    xsb[xbase + (size_t)i*192 + c] = als[c][i];
  }
  __syncthreads();
  size_t dbase = (size_t)((b*4 + k)*64 + s)*384;
  for (int j = tid; j < 384; j += 256){
    int i = j/6, r = j - i*6;
    dlsb[dbase + j] = dls[r][i];
  }
}

// ------------------------------------------------ K11: scan phase A — per-segment (P,Q)
__global__ __launch_bounds__(192) void k_scanA(const float* __restrict__ xsb,
    const float* __restrict__ dlsb, const float* __restrict__ Bsb,
    const float* __restrict__ dtw, const float* __restrict__ dtb,
    const float* __restrict__ alog, float* __restrict__ Pb, float* __restrict__ Qb){
  int bid = blockIdx.x; int s = bid & 63; int k = (bid >> 6) & 3; int b = bid >> 8;
  int c = threadIdx.x; int bk = b*4 + k;
  __shared__ float sdl[384];
  __shared__ float sB[16][64];
  size_t dbase = (size_t)(bk*64 + s)*384;
  for (int j = c; j < 384; j += 192) sdl[j] = dlsb[dbase + j];
  for (int j = c; j < 1024; j += 192){ int n = j >> 6, i = j & 63;
    sB[n][i] = Bsb[((size_t)bk*16 + n)*4096 + (s << 6) + i]; }
  __syncthreads();
  float A[16], P[16], Q[16];
  const float* arow = alog + ((size_t)k*192 + c)*16;
  #pragma unroll
  for (int n = 0; n < 16; n++){ A[n] = -__expf(arow[n]); P[n] = 1.f; Q[n] = 0.f; }
  float dw[6];
  #pragma unroll
  for (int r = 0; r < 6; r++) dw[r] = dtw[((size_t)k*192 + c)*6 + r];
  float db = dtb[k*192 + c];
  const float* xrow = xsb + ((size_t)bk*4096 + (s << 6))*192 + c;
  for (int i = 0; i < 64; i++){
    float u = xrow[(size_t)i*192];
    float acc = db;
    #pragma unroll
    for (int r = 0; r < 6; r++) acc += sdl[i*6 + r]*dw[r];
    float dl = fmaxf(acc, 0.f) + log1pf(__expf(-fabsf(acc)));
    float du = dl*u;
    #pragma unroll
    for (int n = 0; n < 16; n++){
      float e = __expf(dl*A[n]);
      P[n] *= e;
      Q[n] = Q[n]*e + du*sB[n][i];
    }
  }
  size_t pbase = ((size_t)(bk*64 + s)*16)*192 + c;
  #pragma unroll
  for (int n = 0; n < 16; n++){ Pb[pbase + (size_t)n*192] = P[n]; Qb[pbase + (size_t)n*192] = Q[n]; }
}

// ------------------------------------------------ K12: scan phase B — prefix over 64 segments (hin in-place over Pb)
__global__ __launch_bounds__(256) void k_scanB(float* __restrict__ Pb,
    const float* __restrict__ Qb){
  int id = blockIdx.x*256 + threadIdx.x;   // (bk*16+n)*192+c -> 49152
  int c = id % 192; int rest = id / 192; int n = rest % 16; int bk = rest / 16;
  float h = 0.f;
  for (int s = 0; s < 64; s++){
    size_t o = (((size_t)bk*64 + s)*16 + n)*192 + c;
    float P = Pb[o], Q = Qb[o];
    Pb[o] = h;
    h = P*h + Q;
  }
}

// ------------------------------------------------ K13: scan phase C — replay, scatter-add into yb
__global__ __launch_bounds__(192) void k_scanC(const float* __restrict__ xsb,
    const float* __restrict__ dlsb, const float* __restrict__ Bsb, const float* __restrict__ Csb,
    const float* __restrict__ hinb, const float* __restrict__ dtw, const float* __restrict__ dtb,
    const float* __restrict__ alog, const float* __restrict__ Dsp, float* __restrict__ yb){
  int bid = blockIdx.x; int s = bid & 63; int k = (bid >> 6) & 3; int b = bid >> 8;
  int c = threadIdx.x; int bk = b*4 + k;
  __shared__ float sdl[384];
  __shared__ float sB[16][64];
  __shared__ float sC[16][64];
  size_t dbase = (size_t)(bk*64 + s)*384;
  for (int j = c; j < 384; j += 192) sdl[j] = dlsb[dbase + j];
  for (int j = c; j < 1024; j += 192){ int n = j >> 6, i = j & 63;
    size_t o = ((size_t)bk*16 + n)*4096 + (s << 6) + i;
    sB[n][i] = Bsb[o]; sC[n][i] = Csb[o]; }
  __syncthreads();
  float A[16], h[16];
  const float* arow = alog + ((size_t)k*192 + c)*16;
  #pragma unroll
  for (int n = 0; n < 16; n++) A[n] = -__expf(arow[n]);
  size_t hbase = ((size_t)(bk*64 + s)*16)*192 + c;
  #pragma unroll
  for (int n = 0; n < 16; n++) h[n] = hinb[hbase + (size_t)n*192];
  float dw[6];
  #pragma unroll
  for (int r = 0; r < 6; r++) dw[r] = dtw[((size_t)k*192 + c)*6 + r];
  float db = dtb[k*192 + c];
  float Dc = Dsp[k*192 + c];
  const float* xrow = xsb + ((size_t)bk*4096 + (s << 6))*192 + c;
  int p0, pst;
  if (k == 0){ p0 = s << 6;        pst = 1;  }
  else if (k == 1){ p0 = s;        pst = 64; }
  else if (k == 2){ p0 = 4095 - (s << 6); pst = -1; }
  else { p0 = 4095 - s;            pst = -64; }
  for (int i = 0; i < 64; i++){
    float u = xrow[(size_t)i*192];
    float acc = db;
    #pragma unroll
    for (int r = 0; r < 6; r++) acc += sdl[i*6 + r]*dw[r];
    float dl = fmaxf(acc, 0.f) + log1pf(__expf(-fabsf(acc)));
    float du = dl*u;
    float y = 0.f;
    #pragma unroll
    for (int n = 0; n < 16; n++){
      float e = __expf(dl*A[n]);
      h[n] = h[n]*e + du*sB[n][i];
      y += h[n]*sC[n][i];
    }
    y += u*Dc;
    atomicAdd(&yb[((size_t)b*4096 + p0 + pst*i)*192 + c], y);
  }
}

// ------------------------------------------------ K14: symmetry enhance
__global__ __launch_bounds__(256) void k_enh(const float* __restrict__ yb,
    const float* __restrict__ symw, float* __restrict__ yfb){
  int id = blockIdx.x*256 + threadIdx.x;
  int c = id % 192; int rest = id / 192; int l = rest & 4095; int b = rest >> 12;
  int w = l & 63; int lr = (l | 63) - w;
  float v  = yb[id];
  float vr = yb[(((size_t)b << 12) + lr)*192 + c];
  float wg = 1.f/(1.f + __expf(-symw[0]));
  float enh = v*(1.f - wg) + 0.5f*(v + vr)*wg;
  yfb[id] = v + 0.2f*enh;
}

// ------------------------------------------------ K15: LayerNorm + SiLU(z) + out_proj + residual (tiled)
__global__ __launch_bounds__(256) void k_final(const float* __restrict__ yf,
    const float* __restrict__ zT, const float* __restrict__ g, const float* __restrict__ bta,
    const float* __restrict__ opw, const float* __restrict__ x, float* __restrict__ out){
  int og = blockIdx.x & 1; int lt = (blockIdx.x >> 1) & 127; int b = blockIdx.x >> 8;
  int l0 = lt << 5;
  __shared__ float sv[32][193];
  __shared__ float wt[192*48];
  __shared__ float sg[192], sb2[192];
  __shared__ float smu[32], srs[32];
  int tid = threadIdx.x;
  for (int idx = tid; idx < 6144; idx += 256){ int r = idx/192, c = idx - r*192;
    sv[r][c] = yf[((size_t)b*4096 + l0 + r)*192 + c]; }
  if (tid < 192){ sg[tid] = g[tid]; sb2[tid] = bta[tid]; }
  int o0 = og*48;
  for (int idx = tid; idx < 9216; idx += 256){ int o = idx % 48, c = idx/48;
    wt[c*48 + o] = opw[(size_t)(o0 + o)*192 + c]; }
  __syncthreads();
  if (tid < 32){
    float s1 = 0.f, s2 = 0.f;
    for (int c = 0; c < 192; c++){ float v = sv[tid][c]; s1 += v; s2 += v*v; }
    float mu = s1*(1.0f/192.0f);
    smu[tid] = mu; srs[tid] = rsqrtf(s2*(1.0f/192.0f) - mu*mu + 1e-5f);
  }
  __syncthreads();
  for (int idx = tid; idx < 6144; idx += 256){ int l = idx & 31, c = idx >> 5;
    float zv = zT[((size_t)b*192 + c)*4096 + l0 + l];
    float v = sv[l][c];
    float yn = (v - smu[l])*srs[l]*sg[c] + sb2[c];
    sv[l][c] = yn * (zv/(1.f + __expf(-zv)));
  }
  __syncthreads();
  int l = tid & 31, grp = tid >> 5;
  float acc[6];
  #pragma unroll
  for (int j = 0; j < 6; j++) acc[j] = 0.f;
  for (int c = 0; c < 192; c++){
    float svv = sv[l][c];
    const float* wr = &wt[c*48 + grp*6];
    #pragma unroll
    for (int j = 0; j < 6; j += 2){
      float2 w2 = *(const float2*)&wr[j];
      acc[j]   += svv*w2.x; acc[j+1] += svv*w2.y;
    }
  }
  size_t ob = ((size_t)b*4096 + l0 + l)*96 + o0 + grp*6;
  #pragma unroll
  for (int j = 0; j < 6; j++) acc[j] += x[ob + j];
  #pragma unroll
  for (int j = 0; j < 6; j += 2){
    float2 v2; v2.x = acc[j]; v2.y = acc[j+1];
    *(float2*)&out[ob + j] = v2;
  }
}

// ================================================================ host
extern "C" void kernel_launch(void* const* d_in, const int* in_sizes, int n_in,
                              void* d_out, int out_size, void* d_ws, size_t ws_size,
                              hipStream_t stream){
  (void)in_sizes; (void)n_in; (void)out_size; (void)ws_size;
  const float* ix   = (const float*)d_in[0];
  const float* ipw  = (const float*)d_in[1];
  const float* fw1  = (const float*)d_in[2];
  const float* fb1  = (const float*)d_in[3];
  const float* fw2  = (const float*)d_in[4];
  const float* fb2  = (const float*)d_in[5];
  const float* ww   = (const float*)d_in[6];
  const float* wb   = (const float*)d_in[7];
  const float* dww  = (const float*)d_in[8];
  const float* dwb  = (const float*)d_in[9];
  const float* symw = (const float*)d_in[10];
  const float* xpw  = (const float*)d_in[11];
  const float* dtw  = (const float*)d_in[12];
  const float* dtb  = (const float*)d_in[13];
  const float* alog = (const float*)d_in[14];
  const float* Dsp  = (const float*)d_in[15];
  const float* ong  = (const float*)d_in[16];
  const float* onb  = (const float*)d_in[17];
  const float* opw  = (const float*)d_in[18];
  const float* rmsw = (const float*)d_in[19];

  float* W = (float*)d_ws;
  const size_t SZ_BLC = 3145728, SZ_F = 1622016, SZ_H = 786432;
  float* zT  = W;
  float* ab  = zT + SZ_BLC;
  float* R0  = ab + SZ_BLC;
  // phase 1
  float* xc    = R0;
  float* fre   = xc  + SZ_BLC;
  float* fim   = fre + SZ_F;
  float* fab   = fim + SZ_F;
  float* mb    = fab + SZ_F;
  float* llb   = mb  + SZ_F;
  float* lhb   = llb + SZ_H;
  float* wpart = lhb + 3*SZ_H;      // 3 x 2,359,296  (phase1 ends at R0+19,857,408)
  // phase 2 (all phase-1 dead after k_dwconv; ab persists separately)
  float* Bsb  = R0;                  //  1,048,576
  float* Csb  = Bsb + 1048576;       //  1,048,576
  float* dlsb = Csb + 1048576;       //    393,216
  float* xsb  = dlsb + 393216;       // 12,582,912  [bk][l][c]
  float* Pb   = xsb + 12582912;      //  3,145,728  (also aT before scanA)
  float* aT   = Pb;
  float* Qb   = Pb + SZ_BLC;         //  3,145,728
  float* yb   = Qb + SZ_BLC;         //  3,145,728
  float* yfb  = xsb;                 // alias: xsb dead after scanC

  hipLaunchKernelGGL(k_rms_inproj, dim3(2048),   dim3(256), 0, stream, ix, rmsw, ipw, xc, zT);
  hipLaunchKernelGGL(k_dft_fwd,    dim3(4*192),  dim3(256), 0, stream, xc, fre, fim, fab);
  hipLaunchKernelGGL(k_cmix1,      dim3(864),    dim3(256), 0, stream, fab, fw1, fb1, mb);
  hipLaunchKernelGGL(k_cmix2,      dim3(864),    dim3(256), 0, stream, mb, fw2, fb2, fre, fim, fab);
  hipLaunchKernelGGL(k_dwt,        dim3(3072),   dim3(256), 0, stream, xc, llb, lhb, lhb + SZ_H, lhb + 2*SZ_H);
  hipLaunchKernelGGL(k_wconv,      dim3(864),    dim3(256), 0, stream, lhb, ww, wpart);
  hipLaunchKernelGGL(k_fcomb,      dim3(12288),  dim3(256), 0, stream, xc, llb, wpart, wb);
  hipLaunchKernelGGL(k_dft_inv,    dim3(4*192),  dim3(256), 0, stream, fre, fim, xc);
  hipLaunchKernelGGL(k_dwconv,     dim3(12288),  dim3(256), 0, stream, xc, dww, dwb, ab);
  hipLaunchKernelGGL(k_transpose,  dim3(768),    dim3(256), 0, stream, ab, aT);
  hipLaunchKernelGGL(k_xproj,      dim3(1024),   dim3(256), 0, stream, ab, aT, xpw, Bsb, Csb, dlsb, xsb);
  hipLaunchKernelGGL(k_scanA,      dim3(1024),   dim3(192), 0, stream, xsb, dlsb, Bsb, dtw, dtb, alog, Pb, Qb);
  hipLaunchKernelGGL(k_scanB,      dim3(192),    dim3(256), 0, stream, Pb, Qb);
  hipLaunchKernelGGL(k_zero,       dim3(12288),  dim3(256), 0, stream, yb, (int)SZ_BLC);
  hipLaunchKernelGGL(k_scanC,      dim3(1024),   dim3(192), 0, stream, xsb, dlsb, Bsb, Csb, Pb, dtw, dtb, alog, Dsp, yb);
  hipLaunchKernelGGL(k_enh,        dim3(12288),  dim3(256), 0, stream, yb, symw, yfb);
  hipLaunchKernelGGL(k_final,      dim3(1024),   dim3(256), 0, stream, yfb, zT, ong, onb, opw, ix, (float*)d_out);
}